// Round 9
// baseline (712.957 us; speedup 1.0000x reference)
//
#include <hip/hip_runtime.h>
#include <cstddef>

// Problem constants (MultiHeadKvtAttention): B=8, N=1024, DIM=768, H=12, D=64, TOPK=100
#define DIMC 768
#define HEADS 12
#define HEAD_DIM 64
#define TOPK 100
#define SCALE 0.125f
#define BATCH 8
#define SEQ 1024
#define RB 8       // rows per attention block (one 64-lane wave per row)
#define CAP 128    // compacted-index capacity per row (fallback loop if exceeded)
#define ATHR 512   // 8 waves

typedef _Float16 f16;
typedef __attribute__((ext_vector_type(8))) _Float16 f16x8;
typedef __attribute__((ext_vector_type(8))) __bf16 bf16x8;
typedef __attribute__((ext_vector_type(4))) float f32x4;
typedef unsigned short u16;

// Row layout of the qkv workspace (u16 units, stride 4608 = 2304 f32):
//   [0,1536)    : Q fp32 (768 floats)
//   [1536,2304) : Kh fp16 (768)   -- written by GEMM1 epilogue (split)
//   [2304,3072) : Kl fp16 (768)   -- residual
//   [3072,4608) : V fp32 (768 floats)

__device__ __forceinline__ unsigned mkey(float f) {
  // monotonic float->uint transform: a > b  <=>  mkey(a) > mkey(b)
  unsigned u = __float_as_uint(f);
  return u ^ ((unsigned)((int)u >> 31) | 0x80000000u);
}

// Exact 2-way bf16 split for the GEMM operands (error ~2^-17 rel, proven r5).
__device__ __forceinline__ void split_pack4(float4 f, uint2& ph, uint2& pl) {
  unsigned u0 = __float_as_uint(f.x), u1 = __float_as_uint(f.y);
  unsigned u2 = __float_as_uint(f.z), u3 = __float_as_uint(f.w);
  float r0 = f.x - __uint_as_float(u0 & 0xFFFF0000u);
  float r1 = f.y - __uint_as_float(u1 & 0xFFFF0000u);
  float r2 = f.z - __uint_as_float(u2 & 0xFFFF0000u);
  float r3 = f.w - __uint_as_float(u3 & 0xFFFF0000u);
  ph.x = (u0 >> 16) | (u1 & 0xFFFF0000u);
  ph.y = (u2 >> 16) | (u3 & 0xFFFF0000u);
  pl.x = (__float_as_uint(r0) >> 16) | (__float_as_uint(r1) & 0xFFFF0000u);
  pl.y = (__float_as_uint(r2) >> 16) | (__float_as_uint(r3) & 0xFFFF0000u);
}

// ---------------------------------------------------------------------------
// Split-bf16 MFMA GEMM (3-term, fp32-accurate). KSPLIT: tiles whose columns
// fall in [768,1536) (the K third of qkv) are written as fp16 hi/lo pairs
// in-place (same bytes as the fp32 K would occupy) instead of fp32.
// (unchanged from round 5 — measured ~170 us combined)
// ---------------------------------------------------------------------------
template <int A_SPLIT, bool BIAS, bool KSPLIT>
__global__ __launch_bounds__(256) void gemm_mfma_split(
    const float* __restrict__ Af,
    const u16* __restrict__ Ah_g, const u16* __restrict__ Al_g,
    const float* __restrict__ W,
    const float* __restrict__ bias, float* __restrict__ C,
    int M, int K, int N) {
  __shared__ u16 Ah[128][32], Al[128][32];  // [m][k]
  __shared__ u16 Bh[128][32], Bl[128][32];  // [n][k] (transposed W)

  const int t = threadIdx.x;
  const int w = t >> 6, l = t & 63;
  const int wr = w >> 1, wc = w & 1;
  const int row0 = blockIdx.y * 128, col0 = blockIdx.x * 128;
  const int fr = l & 15, fq = l >> 4;

  f32x4 acc[4][4];
#pragma unroll
  for (int i = 0; i < 4; ++i)
#pragma unroll
    for (int j = 0; j < 4; ++j) acc[i][j] = (f32x4){0.f, 0.f, 0.f, 0.f};

  const int a_row = t >> 1;
  const int a_k0 = (t & 1) * 16;
  const int w_col = t & 127;
  const int w_kh = (t >> 7) * 16;

  for (int k0 = 0; k0 < K; k0 += 32) {
    if constexpr (A_SPLIT == 0) {
      const float* ap = Af + (size_t)(row0 + a_row) * K + k0 + a_k0;
#pragma unroll
      for (int q = 0; q < 4; ++q) {
        float4 v = *(const float4*)(ap + q * 4);
        uint2 ph, pl;
        split_pack4(v, ph, pl);
        *(uint2*)&Ah[a_row][a_k0 + q * 4] = ph;
        *(uint2*)&Al[a_row][a_k0 + q * 4] = pl;
      }
    } else {
      const size_t off = (size_t)(row0 + a_row) * K + k0 + a_k0;
      *(uint4*)&Ah[a_row][a_k0] = *(const uint4*)(Ah_g + off);
      *(uint4*)&Ah[a_row][a_k0 + 8] = *(const uint4*)(Ah_g + off + 8);
      *(uint4*)&Al[a_row][a_k0] = *(const uint4*)(Al_g + off);
      *(uint4*)&Al[a_row][a_k0 + 8] = *(const uint4*)(Al_g + off + 8);
    }
    {
      const float* wp = W + (size_t)(k0 + w_kh) * N + col0 + w_col;
      float wv[16];
#pragma unroll
      for (int j = 0; j < 16; ++j) wv[j] = wp[(size_t)j * N];
#pragma unroll
      for (int g = 0; g < 4; ++g) {
        float4 v = make_float4(wv[g * 4], wv[g * 4 + 1], wv[g * 4 + 2], wv[g * 4 + 3]);
        uint2 ph, pl;
        split_pack4(v, ph, pl);
        *(uint2*)&Bh[w_col][w_kh + g * 4] = ph;
        *(uint2*)&Bl[w_col][w_kh + g * 4] = pl;
      }
    }
    __syncthreads();

    bf16x8 fah[4], fal[4], fbh[4], fbl[4];
#pragma unroll
    for (int mf = 0; mf < 4; ++mf) {
      fah[mf] = *(const bf16x8*)&Ah[wr * 64 + mf * 16 + fr][fq * 8];
      fal[mf] = *(const bf16x8*)&Al[wr * 64 + mf * 16 + fr][fq * 8];
    }
#pragma unroll
    for (int nf = 0; nf < 4; ++nf) {
      fbh[nf] = *(const bf16x8*)&Bh[wc * 64 + nf * 16 + fr][fq * 8];
      fbl[nf] = *(const bf16x8*)&Bl[wc * 64 + nf * 16 + fr][fq * 8];
    }
#pragma unroll
    for (int mf = 0; mf < 4; ++mf)
#pragma unroll
      for (int nf = 0; nf < 4; ++nf) {
        acc[mf][nf] = __builtin_amdgcn_mfma_f32_16x16x32_bf16(fah[mf], fbh[nf], acc[mf][nf], 0, 0, 0);
        acc[mf][nf] = __builtin_amdgcn_mfma_f32_16x16x32_bf16(fah[mf], fbl[nf], acc[mf][nf], 0, 0, 0);
        acc[mf][nf] = __builtin_amdgcn_mfma_f32_16x16x32_bf16(fal[mf], fbh[nf], acc[mf][nf], 0, 0, 0);
      }
    __syncthreads();
  }

  // ---- epilogue ----
  const bool kzone = KSPLIT && (col0 >= 768) && (col0 < 1536);
#pragma unroll
  for (int mf = 0; mf < 4; ++mf) {
    const int r0 = row0 + wr * 64 + mf * 16 + fq * 4;
#pragma unroll
    for (int nf = 0; nf < 4; ++nf) {
      const int c = col0 + wc * 64 + nf * 16 + fr;
      if (kzone) {
        // write fp16 hi/lo split in-place: kh at u16[1536+(c-768)] = [c+768],
        // kl at u16[2304+(c-768)] = [c+1536] within the 4608-u16 row
        f16* cb = (f16*)C;
#pragma unroll
        for (int r = 0; r < 4; ++r) {
          float v = acc[mf][nf][r];
          f16 hh = (f16)v;
          f16 hl = (f16)(v - (float)hh);
          f16* rp = cb + (size_t)(r0 + r) * 4608;
          rp[c + 768] = hh;
          rp[c + 1536] = hl;
        }
      } else {
        float bb = 0.f;
        if (BIAS) bb = bias[c];
#pragma unroll
        for (int r = 0; r < 4; ++r)
          C[(size_t)(r0 + r) * N + c] = acc[mf][nf][r] + bb;
      }
    }
  }
}

// ---------------------------------------------------------------------------
// Fused attention, exact top-k, MFMA scores.
// Round-9 changes vs round-8 (both target the measured latency stall:
// VALUBusy 43%, MfmaUtil 7%, nothing saturated):
//  1. XCD-locality: grid is (B*H=96, SEQ/RB=128). Flat dispatch id =
//     bh + y*96 and 96 % 8 == 0, so ALL row-blocks of one (b,h) land on
//     XCD bh%8 -> its 256 KB K-panel stays in that XCD's 4 MB L2
//     (12 panels/XCD ~ 3 MB) instead of 96 panels thrashing globally.
//  2. Q fragments built in registers from global (bit-exact same values):
//     kills the Qh/Ql LDS (4 KB) and one barrier. LDS 38.9 KB ->
//     4 blocks/CU = 32 waves = 100% occupancy.
// ---------------------------------------------------------------------------
__global__ __launch_bounds__(ATHR) void attn_topk(
    const float* __restrict__ qkv,
    u16* __restrict__ aout_h, u16* __restrict__ aout_l) {
  __shared__ float s[RB][SEQ];                     // 32 KB scores
  __shared__ unsigned short idxl[RB][CAP];         // 2 KB
  __shared__ float pl[RB][CAP];                    // 4 KB
  // total 38.9 KB -> 4 blocks/CU

  const int t = threadIdx.x;
  const int bh = blockIdx.x;                 // XCD = bh % 8 (flat%8 heuristic)
  const int n0 = blockIdx.y * RB;
  const int b = bh / HEADS, h = bh - b * HEADS;
  const float* qf = qkv + (size_t)b * SEQ * (3 * DIMC);      // b's f32 rows
  const f16* kb = (const f16*)qkv + (size_t)b * SEQ * 4608 + 1536 + h * 64;
  // row n: kh = kb + n*4608 (+768 for kl)

  const int w = t >> 6, l = t & 63;
  const int fr = l & 15, fq = l >> 4;

  // ---- Q fragments in registers (A map: row=fr, k=fq*8+reg; 2nd k-step +32).
  //      fr&7: rows 8-15 of the A operand duplicate rows 0-7 (their MFMA
  //      output rows are discarded; avoids OOB at the batch tail). ----
  f16x8 ah0, al0, ah1, al1;
  {
    const float* qp = qf + (size_t)(n0 + (fr & 7)) * (3 * DIMC) + h * 64 + fq * 8;
    float4 qa = *(const float4*)(qp);
    float4 qb = *(const float4*)(qp + 4);
    float4 qc = *(const float4*)(qp + 32);
    float4 qd = *(const float4*)(qp + 36);
    float v0[8] = {qa.x, qa.y, qa.z, qa.w, qb.x, qb.y, qb.z, qb.w};
    float v1[8] = {qc.x, qc.y, qc.z, qc.w, qd.x, qd.y, qd.z, qd.w};
#pragma unroll
    for (int j = 0; j < 8; ++j) {
      float q0 = v0[j] * SCALE;
      f16 hh0 = (f16)q0;
      ah0[j] = hh0;
      al0[j] = (f16)(q0 - (float)hh0);
      float q1 = v1[j] * SCALE;
      f16 hh1 = (f16)q1;
      ah1[j] = hh1;
      al1[j] = (f16)(q1 - (float)hh1);
    }
  }

  // ---- scores via MFMA: wave w owns col-tiles [w*8, w*8+8) ----
  {
#pragma unroll
    for (int i = 0; i < 8; ++i) {
      const int tile = w * 8 + i;
      const f16* kr = kb + (size_t)(tile * 16 + fr) * 4608;
      f16x8 bh0 = *(const f16x8*)(kr + fq * 8);
      f16x8 bh1 = *(const f16x8*)(kr + 32 + fq * 8);
      f16x8 bl0 = *(const f16x8*)(kr + 768 + fq * 8);
      f16x8 bl1 = *(const f16x8*)(kr + 768 + 32 + fq * 8);
      f32x4 acc = (f32x4){0.f, 0.f, 0.f, 0.f};
      acc = __builtin_amdgcn_mfma_f32_16x16x32_f16(ah0, bh0, acc, 0, 0, 0);
      acc = __builtin_amdgcn_mfma_f32_16x16x32_f16(ah0, bl0, acc, 0, 0, 0);
      acc = __builtin_amdgcn_mfma_f32_16x16x32_f16(al0, bh0, acc, 0, 0, 0);
      acc = __builtin_amdgcn_mfma_f32_16x16x32_f16(ah1, bh1, acc, 0, 0, 0);
      acc = __builtin_amdgcn_mfma_f32_16x16x32_f16(ah1, bl1, acc, 0, 0, 0);
      acc = __builtin_amdgcn_mfma_f32_16x16x32_f16(al1, bh1, acc, 0, 0, 0);
      if (fq < 2) {  // C/D row = fq*4+r (keep rows 0-7), col = tile*16+fr
#pragma unroll
        for (int r = 0; r < 4; ++r) s[fq * 4 + r][tile * 16 + fr] = acc[r];
      }
    }
  }
  __syncthreads();
  // ======== everything below is wave-local (wave w owns row w) ========

  const int row = w;

  // ---- pull row scores into registers: lane l owns cols l + 64j ----
  float sc[16];
  unsigned ky[16];
#pragma unroll
  for (int j = 0; j < 16; ++j) sc[j] = s[row][l + 64 * j];
#pragma unroll
  for (int j = 0; j < 16; ++j) ky[j] = mkey(sc[j]);

  // ---- exact k-th largest key via bisection; ballot+popcll counting ----
  unsigned cur = 0u;
  for (int bit = 31; bit >= 0; --bit) {
    const unsigned T = cur | (1u << bit);
    int c = 0;
#pragma unroll
    for (int j = 0; j < 16; ++j)
      c += (int)__popcll(__ballot(ky[j] >= T));
    if (c >= TOPK) {  // c is scalar-uniform -> no divergence
      cur = T;
      if (c == TOPK) break;
    }
  }

  // ---- row max ----
  float mx = sc[0];
#pragma unroll
  for (int j = 1; j < 16; ++j) mx = fmaxf(mx, sc[j]);
#pragma unroll
  for (int off = 32; off > 0; off >>= 1) mx = fmaxf(mx, __shfl_xor(mx, off, 64));

  // ---- masked exp + sum + ballot compaction (single pass) ----
  float sum = 0.f;
  unsigned cbase = 0;
#pragma unroll
  for (int j = 0; j < 16; ++j) {
    const bool keep = ky[j] >= cur;  // matches reference `attn >= kth`
    const float e = keep ? __expf(sc[j] - mx) : 0.f;
    sum += e;
    const unsigned long long mask = __ballot(keep);
    if (keep) {
      const unsigned pos = cbase + (unsigned)__popcll(mask & ((1ull << l) - 1ull));
      if (pos < CAP) {
        idxl[row][pos] = (unsigned short)(l + 64 * j);
        pl[row][pos] = e;
      }
    }
    cbase += (unsigned)__popcll(mask);
  }
  const unsigned cnt = cbase;  // uniform
#pragma unroll
  for (int off = 32; off > 0; off >>= 1) sum += __shfl_xor(sum, off, 64);
  const float rinv = 1.f / sum;

  // ---- PV: sparse gather, scalar row bases via readfirstlane ----
  {
    const float* vb = qf + 1536 + h * 64;  // V f32 base (row stride 2304 f32)
    float o = 0.f;
    if (cnt <= CAP) {
      unsigned j = 0;
      for (; j + 8 <= cnt; j += 8) {
        float pv[8], vv[8];
#pragma unroll
        for (int q = 0; q < 8; ++q) {
          const int m = __builtin_amdgcn_readfirstlane((int)idxl[row][j + q]);
          vv[q] = vb[(size_t)m * (3 * DIMC) + l];
          pv[q] = pl[row][j + q];
        }
#pragma unroll
        for (int q = 0; q < 8; ++q) o = fmaf(pv[q], vv[q], o);
      }
      for (; j < cnt; ++j) {
        const int m = __builtin_amdgcn_readfirstlane((int)idxl[row][j]);
        o = fmaf(pl[row][j], vb[(size_t)m * (3 * DIMC) + l], o);
      }
    } else {  // tie-overflow fallback (cnt > CAP: vanishingly rare)
      for (int m = 0; m < SEQ; ++m) {
        float v = s[row][m];
        if (mkey(v) >= cur) o = fmaf(__expf(v - mx), vb[(size_t)m * (3 * DIMC) + l], o);
      }
    }
    // write output as exact hi/lo bf16 split (consumed by MFMA proj GEMM)
    const float r = o * rinv;
    const unsigned u = __float_as_uint(r);
    const float rl = r - __uint_as_float(u & 0xFFFF0000u);
    const size_t idx = ((size_t)b * SEQ + n0 + row) * DIMC + h * 64 + l;
    aout_h[idx] = (u16)(u >> 16);
    aout_l[idx] = (u16)(__float_as_uint(rl) >> 16);
  }
}

// ---------------------------------------------------------------------------
extern "C" void kernel_launch(void* const* d_in, const int* in_sizes, int n_in,
                              void* d_out, int out_size, void* d_ws, size_t ws_size,
                              hipStream_t stream) {
  (void)in_sizes; (void)n_in; (void)out_size; (void)ws_size;
  const float* x      = (const float*)d_in[0];  // [8,1024,768]
  const float* w_qkv  = (const float*)d_in[1];  // [768,2304]
  const float* w_proj = (const float*)d_in[2];  // [768,768]
  const float* b_proj = (const float*)d_in[3];  // [768]
  float* out = (float*)d_out;                   // [8,1024,768]

  const int M = BATCH * SEQ;                    // 8192
  float* qkv = (float*)d_ws;                    // [8192, 2304] (75.5 MB; K third holds fp16 splits)
  u16* ah2 = (u16*)(qkv + (size_t)M * (3 * DIMC));  // [8192,768] bf16-hi (12.6 MB)
  u16* al2 = ah2 + (size_t)M * DIMC;                // [8192,768] bf16-lo (12.6 MB)
  // total ws = 100.66 MB (unchanged from proven layout)

  // 1) QKV projection (split-bf16 MFMA; K tiles written as fp16 hi/lo in-place)
  dim3 g1((3 * DIMC) / 128, M / 128);
  gemm_mfma_split<0, false, true><<<g1, dim3(256), 0, stream>>>(
      x, nullptr, nullptr, w_qkv, nullptr, qkv, M, DIMC, 3 * DIMC);
  // 2) fused top-k attention; grid (bh, row-block) for XCD L2 locality
  dim3 g2(BATCH * HEADS, SEQ / RB);
  attn_topk<<<g2, dim3(ATHR), 0, stream>>>(qkv, ah2, al2);
  // 3) output projection + bias (A pre-split by attn)
  dim3 g3(DIMC / 128, M / 128);
  gemm_mfma_split<1, true, false><<<g3, dim3(256), 0, stream>>>(
      nullptr, ah2, al2, w_proj, b_proj, out, M, DIMC, DIMC);
}

// Round 10
// 707.371 us; speedup vs baseline: 1.0079x; 1.0079x over previous
//
#include <hip/hip_runtime.h>
#include <cstddef>

// Problem constants (MultiHeadKvtAttention): B=8, N=1024, DIM=768, H=12, D=64, TOPK=100
#define DIMC 768
#define HEADS 12
#define HEAD_DIM 64
#define TOPK 100
#define SCALE 0.125f
#define BATCH 8
#define SEQ 1024
#define RB 8       // rows per attention block (one 64-lane wave per row)
#define CAP 128    // compacted-index capacity per row (fallback loop if exceeded)
#define ATHR 512   // 8 waves

typedef _Float16 f16;
typedef __attribute__((ext_vector_type(8))) _Float16 f16x8;
typedef __attribute__((ext_vector_type(8))) __bf16 bf16x8;
typedef __attribute__((ext_vector_type(4))) float f32x4;
typedef unsigned short u16;

// Row layout of the qkv workspace (u16 units, stride 4608 = 2304 f32):
//   [0,1536)    : Q fp32 (768 floats)
//   [1536,2304) : Kh fp16 (768)   -- written by GEMM1 epilogue (split)
//   [2304,3072) : Kl fp16 (768)   -- residual
//   [3072,4608) : V fp32 (768 floats)

__device__ __forceinline__ unsigned mkey(float f) {
  // monotonic float->uint transform: a > b  <=>  mkey(a) > mkey(b)
  unsigned u = __float_as_uint(f);
  return u ^ ((unsigned)((int)u >> 31) | 0x80000000u);
}

// Exact 2-way bf16 split for the GEMM operands (error ~2^-17 rel, proven r5).
__device__ __forceinline__ void split_pack4(float4 f, uint2& ph, uint2& pl) {
  unsigned u0 = __float_as_uint(f.x), u1 = __float_as_uint(f.y);
  unsigned u2 = __float_as_uint(f.z), u3 = __float_as_uint(f.w);
  float r0 = f.x - __uint_as_float(u0 & 0xFFFF0000u);
  float r1 = f.y - __uint_as_float(u1 & 0xFFFF0000u);
  float r2 = f.z - __uint_as_float(u2 & 0xFFFF0000u);
  float r3 = f.w - __uint_as_float(u3 & 0xFFFF0000u);
  ph.x = (u0 >> 16) | (u1 & 0xFFFF0000u);
  ph.y = (u2 >> 16) | (u3 & 0xFFFF0000u);
  pl.x = (__float_as_uint(r0) >> 16) | (__float_as_uint(r1) & 0xFFFF0000u);
  pl.y = (__float_as_uint(r2) >> 16) | (__float_as_uint(r3) & 0xFFFF0000u);
}

// ---------------------------------------------------------------------------
// Split-bf16 MFMA GEMM (3-term, fp32-accurate). KSPLIT: tiles whose columns
// fall in [768,1536) (the K third of qkv) are written as fp16 hi/lo pairs
// in-place (same bytes as the fp32 K would occupy) instead of fp32.
// (unchanged from round 5 — measured ~170 us combined)
// ---------------------------------------------------------------------------
template <int A_SPLIT, bool BIAS, bool KSPLIT>
__global__ __launch_bounds__(256) void gemm_mfma_split(
    const float* __restrict__ Af,
    const u16* __restrict__ Ah_g, const u16* __restrict__ Al_g,
    const float* __restrict__ W,
    const float* __restrict__ bias, float* __restrict__ C,
    int M, int K, int N) {
  __shared__ u16 Ah[128][32], Al[128][32];  // [m][k]
  __shared__ u16 Bh[128][32], Bl[128][32];  // [n][k] (transposed W)

  const int t = threadIdx.x;
  const int w = t >> 6, l = t & 63;
  const int wr = w >> 1, wc = w & 1;
  const int row0 = blockIdx.y * 128, col0 = blockIdx.x * 128;
  const int fr = l & 15, fq = l >> 4;

  f32x4 acc[4][4];
#pragma unroll
  for (int i = 0; i < 4; ++i)
#pragma unroll
    for (int j = 0; j < 4; ++j) acc[i][j] = (f32x4){0.f, 0.f, 0.f, 0.f};

  const int a_row = t >> 1;
  const int a_k0 = (t & 1) * 16;
  const int w_col = t & 127;
  const int w_kh = (t >> 7) * 16;

  for (int k0 = 0; k0 < K; k0 += 32) {
    if constexpr (A_SPLIT == 0) {
      const float* ap = Af + (size_t)(row0 + a_row) * K + k0 + a_k0;
#pragma unroll
      for (int q = 0; q < 4; ++q) {
        float4 v = *(const float4*)(ap + q * 4);
        uint2 ph, pl;
        split_pack4(v, ph, pl);
        *(uint2*)&Ah[a_row][a_k0 + q * 4] = ph;
        *(uint2*)&Al[a_row][a_k0 + q * 4] = pl;
      }
    } else {
      const size_t off = (size_t)(row0 + a_row) * K + k0 + a_k0;
      *(uint4*)&Ah[a_row][a_k0] = *(const uint4*)(Ah_g + off);
      *(uint4*)&Ah[a_row][a_k0 + 8] = *(const uint4*)(Ah_g + off + 8);
      *(uint4*)&Al[a_row][a_k0] = *(const uint4*)(Al_g + off);
      *(uint4*)&Al[a_row][a_k0 + 8] = *(const uint4*)(Al_g + off + 8);
    }
    {
      const float* wp = W + (size_t)(k0 + w_kh) * N + col0 + w_col;
      float wv[16];
#pragma unroll
      for (int j = 0; j < 16; ++j) wv[j] = wp[(size_t)j * N];
#pragma unroll
      for (int g = 0; g < 4; ++g) {
        float4 v = make_float4(wv[g * 4], wv[g * 4 + 1], wv[g * 4 + 2], wv[g * 4 + 3]);
        uint2 ph, pl;
        split_pack4(v, ph, pl);
        *(uint2*)&Bh[w_col][w_kh + g * 4] = ph;
        *(uint2*)&Bl[w_col][w_kh + g * 4] = pl;
      }
    }
    __syncthreads();

    bf16x8 fah[4], fal[4], fbh[4], fbl[4];
#pragma unroll
    for (int mf = 0; mf < 4; ++mf) {
      fah[mf] = *(const bf16x8*)&Ah[wr * 64 + mf * 16 + fr][fq * 8];
      fal[mf] = *(const bf16x8*)&Al[wr * 64 + mf * 16 + fr][fq * 8];
    }
#pragma unroll
    for (int nf = 0; nf < 4; ++nf) {
      fbh[nf] = *(const bf16x8*)&Bh[wc * 64 + nf * 16 + fr][fq * 8];
      fbl[nf] = *(const bf16x8*)&Bl[wc * 64 + nf * 16 + fr][fq * 8];
    }
#pragma unroll
    for (int mf = 0; mf < 4; ++mf)
#pragma unroll
      for (int nf = 0; nf < 4; ++nf) {
        acc[mf][nf] = __builtin_amdgcn_mfma_f32_16x16x32_bf16(fah[mf], fbh[nf], acc[mf][nf], 0, 0, 0);
        acc[mf][nf] = __builtin_amdgcn_mfma_f32_16x16x32_bf16(fah[mf], fbl[nf], acc[mf][nf], 0, 0, 0);
        acc[mf][nf] = __builtin_amdgcn_mfma_f32_16x16x32_bf16(fal[mf], fbh[nf], acc[mf][nf], 0, 0, 0);
      }
    __syncthreads();
  }

  // ---- epilogue ----
  const bool kzone = KSPLIT && (col0 >= 768) && (col0 < 1536);
#pragma unroll
  for (int mf = 0; mf < 4; ++mf) {
    const int r0 = row0 + wr * 64 + mf * 16 + fq * 4;
#pragma unroll
    for (int nf = 0; nf < 4; ++nf) {
      const int c = col0 + wc * 64 + nf * 16 + fr;
      if (kzone) {
        // write fp16 hi/lo split in-place: kh at u16[1536+(c-768)] = [c+768],
        // kl at u16[2304+(c-768)] = [c+1536] within the 4608-u16 row
        f16* cb = (f16*)C;
#pragma unroll
        for (int r = 0; r < 4; ++r) {
          float v = acc[mf][nf][r];
          f16 hh = (f16)v;
          f16 hl = (f16)(v - (float)hh);
          f16* rp = cb + (size_t)(r0 + r) * 4608;
          rp[c + 768] = hh;
          rp[c + 1536] = hl;
        }
      } else {
        float bb = 0.f;
        if (BIAS) bb = bias[c];
#pragma unroll
        for (int r = 0; r < 4; ++r)
          C[(size_t)(r0 + r) * N + c] = acc[mf][nf][r] + bb;
      }
    }
  }
}

// ---------------------------------------------------------------------------
// Fused attention, exact top-k, MFMA scores, Q fragments in registers.
// Grid is (SEQ/RB, B*H) — round-8 ordering, RESTORED after round 9 showed
// the transposed grid blew L2 misses up 4.7x (978 MB fetch): the concurrent
// block cohort must share both the K-panel AND one batch's V-gather region.
// Do not "optimize" this grid without watching FETCH_SIZE.
// LDS 38.9 KB -> 4 blocks/CU (~87% occupancy measured in round 9).
// ---------------------------------------------------------------------------
__global__ __launch_bounds__(ATHR) void attn_topk(
    const float* __restrict__ qkv,
    u16* __restrict__ aout_h, u16* __restrict__ aout_l) {
  __shared__ float s[RB][SEQ];                     // 32 KB scores
  __shared__ unsigned short idxl[RB][CAP];         // 2 KB
  __shared__ float pl[RB][CAP];                    // 4 KB

  const int t = threadIdx.x;
  const int n0 = blockIdx.x * RB;            // row-block: FASTEST grid dim
  const int bh = blockIdx.y;
  const int b = bh / HEADS, h = bh - b * HEADS;
  const float* qf = qkv + (size_t)b * SEQ * (3 * DIMC);      // b's f32 rows
  const f16* kb = (const f16*)qkv + (size_t)b * SEQ * 4608 + 1536 + h * 64;
  // row n: kh = kb + n*4608 (+768 for kl)

  const int w = t >> 6, l = t & 63;
  const int fr = l & 15, fq = l >> 4;

  // ---- Q fragments in registers (A map: row=fr, k=fq*8+reg; 2nd k-step +32).
  //      fr&7: rows 8-15 of the A operand duplicate rows 0-7 (their MFMA
  //      output rows are discarded). Bit-exact vs the LDS-staged variant. ----
  f16x8 ah0, al0, ah1, al1;
  {
    const float* qp = qf + (size_t)(n0 + (fr & 7)) * (3 * DIMC) + h * 64 + fq * 8;
    float4 qa = *(const float4*)(qp);
    float4 qb = *(const float4*)(qp + 4);
    float4 qc = *(const float4*)(qp + 32);
    float4 qd = *(const float4*)(qp + 36);
    float v0[8] = {qa.x, qa.y, qa.z, qa.w, qb.x, qb.y, qb.z, qb.w};
    float v1[8] = {qc.x, qc.y, qc.z, qc.w, qd.x, qd.y, qd.z, qd.w};
#pragma unroll
    for (int j = 0; j < 8; ++j) {
      float q0 = v0[j] * SCALE;
      f16 hh0 = (f16)q0;
      ah0[j] = hh0;
      al0[j] = (f16)(q0 - (float)hh0);
      float q1 = v1[j] * SCALE;
      f16 hh1 = (f16)q1;
      ah1[j] = hh1;
      al1[j] = (f16)(q1 - (float)hh1);
    }
  }

  // ---- scores via MFMA: wave w owns col-tiles [w*8, w*8+8) ----
  {
#pragma unroll
    for (int i = 0; i < 8; ++i) {
      const int tile = w * 8 + i;
      const f16* kr = kb + (size_t)(tile * 16 + fr) * 4608;
      f16x8 bh0 = *(const f16x8*)(kr + fq * 8);
      f16x8 bh1 = *(const f16x8*)(kr + 32 + fq * 8);
      f16x8 bl0 = *(const f16x8*)(kr + 768 + fq * 8);
      f16x8 bl1 = *(const f16x8*)(kr + 768 + 32 + fq * 8);
      f32x4 acc = (f32x4){0.f, 0.f, 0.f, 0.f};
      acc = __builtin_amdgcn_mfma_f32_16x16x32_f16(ah0, bh0, acc, 0, 0, 0);
      acc = __builtin_amdgcn_mfma_f32_16x16x32_f16(ah0, bl0, acc, 0, 0, 0);
      acc = __builtin_amdgcn_mfma_f32_16x16x32_f16(al0, bh0, acc, 0, 0, 0);
      acc = __builtin_amdgcn_mfma_f32_16x16x32_f16(ah1, bh1, acc, 0, 0, 0);
      acc = __builtin_amdgcn_mfma_f32_16x16x32_f16(ah1, bl1, acc, 0, 0, 0);
      acc = __builtin_amdgcn_mfma_f32_16x16x32_f16(al1, bh1, acc, 0, 0, 0);
      if (fq < 2) {  // C/D row = fq*4+r (keep rows 0-7), col = tile*16+fr
#pragma unroll
        for (int r = 0; r < 4; ++r) s[fq * 4 + r][tile * 16 + fr] = acc[r];
      }
    }
  }
  __syncthreads();
  // ======== everything below is wave-local (wave w owns row w) ========

  const int row = w;

  // ---- pull row scores into registers: lane l owns cols l + 64j ----
  float sc[16];
  unsigned ky[16];
#pragma unroll
  for (int j = 0; j < 16; ++j) sc[j] = s[row][l + 64 * j];
#pragma unroll
  for (int j = 0; j < 16; ++j) ky[j] = mkey(sc[j]);

  // ---- exact k-th largest key via bisection; ballot+popcll counting ----
  unsigned cur = 0u;
  for (int bit = 31; bit >= 0; --bit) {
    const unsigned T = cur | (1u << bit);
    int c = 0;
#pragma unroll
    for (int j = 0; j < 16; ++j)
      c += (int)__popcll(__ballot(ky[j] >= T));
    if (c >= TOPK) {  // c is scalar-uniform -> no divergence
      cur = T;
      if (c == TOPK) break;
    }
  }

  // ---- row max ----
  float mx = sc[0];
#pragma unroll
  for (int j = 1; j < 16; ++j) mx = fmaxf(mx, sc[j]);
#pragma unroll
  for (int off = 32; off > 0; off >>= 1) mx = fmaxf(mx, __shfl_xor(mx, off, 64));

  // ---- masked exp + sum + ballot compaction (single pass) ----
  float sum = 0.f;
  unsigned cbase = 0;
#pragma unroll
  for (int j = 0; j < 16; ++j) {
    const bool keep = ky[j] >= cur;  // matches reference `attn >= kth`
    const float e = keep ? __expf(sc[j] - mx) : 0.f;
    sum += e;
    const unsigned long long mask = __ballot(keep);
    if (keep) {
      const unsigned pos = cbase + (unsigned)__popcll(mask & ((1ull << l) - 1ull));
      if (pos < CAP) {
        idxl[row][pos] = (unsigned short)(l + 64 * j);
        pl[row][pos] = e;
      }
    }
    cbase += (unsigned)__popcll(mask);
  }
  const unsigned cnt = cbase;  // uniform
#pragma unroll
  for (int off = 32; off > 0; off >>= 1) sum += __shfl_xor(sum, off, 64);
  const float rinv = 1.f / sum;

  // ---- PV: sparse gather, scalar row bases via readfirstlane ----
  {
    const float* vb = qf + 1536 + h * 64;  // V f32 base (row stride 2304 f32)
    float o = 0.f;
    if (cnt <= CAP) {
      unsigned j = 0;
      for (; j + 8 <= cnt; j += 8) {
        float pv[8], vv[8];
#pragma unroll
        for (int q = 0; q < 8; ++q) {
          const int m = __builtin_amdgcn_readfirstlane((int)idxl[row][j + q]);
          vv[q] = vb[(size_t)m * (3 * DIMC) + l];
          pv[q] = pl[row][j + q];
        }
#pragma unroll
        for (int q = 0; q < 8; ++q) o = fmaf(pv[q], vv[q], o);
      }
      for (; j < cnt; ++j) {
        const int m = __builtin_amdgcn_readfirstlane((int)idxl[row][j]);
        o = fmaf(pl[row][j], vb[(size_t)m * (3 * DIMC) + l], o);
      }
    } else {  // tie-overflow fallback (cnt > CAP: vanishingly rare)
      for (int m = 0; m < SEQ; ++m) {
        float v = s[row][m];
        if (mkey(v) >= cur) o = fmaf(__expf(v - mx), vb[(size_t)m * (3 * DIMC) + l], o);
      }
    }
    // write output as exact hi/lo bf16 split (consumed by MFMA proj GEMM)
    const float r = o * rinv;
    const unsigned u = __float_as_uint(r);
    const float rl = r - __uint_as_float(u & 0xFFFF0000u);
    const size_t idx = ((size_t)b * SEQ + n0 + row) * DIMC + h * 64 + l;
    aout_h[idx] = (u16)(u >> 16);
    aout_l[idx] = (u16)(__float_as_uint(rl) >> 16);
  }
}

// ---------------------------------------------------------------------------
extern "C" void kernel_launch(void* const* d_in, const int* in_sizes, int n_in,
                              void* d_out, int out_size, void* d_ws, size_t ws_size,
                              hipStream_t stream) {
  (void)in_sizes; (void)n_in; (void)out_size; (void)ws_size;
  const float* x      = (const float*)d_in[0];  // [8,1024,768]
  const float* w_qkv  = (const float*)d_in[1];  // [768,2304]
  const float* w_proj = (const float*)d_in[2];  // [768,768]
  const float* b_proj = (const float*)d_in[3];  // [768]
  float* out = (float*)d_out;                   // [8,1024,768]

  const int M = BATCH * SEQ;                    // 8192
  float* qkv = (float*)d_ws;                    // [8192, 2304] (75.5 MB; K third holds fp16 splits)
  u16* ah2 = (u16*)(qkv + (size_t)M * (3 * DIMC));  // [8192,768] bf16-hi (12.6 MB)
  u16* al2 = ah2 + (size_t)M * DIMC;                // [8192,768] bf16-lo (12.6 MB)
  // total ws = 100.66 MB (unchanged from proven layout)

  // 1) QKV projection (split-bf16 MFMA; K tiles written as fp16 hi/lo in-place)
  dim3 g1((3 * DIMC) / 128, M / 128);
  gemm_mfma_split<0, false, true><<<g1, dim3(256), 0, stream>>>(
      x, nullptr, nullptr, w_qkv, nullptr, qkv, M, DIMC, 3 * DIMC);
  // 2) fused top-k attention; grid (row-block fastest, bh) — L2-friendly
  dim3 g2(SEQ / RB, BATCH * HEADS);
  attn_topk<<<g2, dim3(ATHR), 0, stream>>>(qkv, ah2, al2);
  // 3) output projection + bias (A pre-split by attn)
  dim3 g3(DIMC / 128, M / 128);
  gemm_mfma_split<1, true, false><<<g3, dim3(256), 0, stream>>>(
      nullptr, ah2, al2, w_proj, b_proj, out, M, DIMC, DIMC);
}